// Round 9
// baseline (419.785 us; speedup 1.0000x reference)
//
#include <hip/hip_runtime.h>
#include <hip/hip_bf16.h>
#include <cstdint>

// ---------------- problem constants ----------------
#define NN      8192      // nodes
#define OF      64        // out features
#define KC      16        // K-chunks
#define CW      512       // K width per chunk (elements)
#define PSTR    65        // P slab row stride (floats): 64 cols + S
#define RBYTES  1024      // bitmask bytes per row (8192/8)

// ---------------- ws layout (bytes) ----------------
#define OFF_HW  0                           // HW 80x8192 u16       = 1310720
#define OFF_P   1310720                     // P16 16x8192x65 f32   = 34078720
#define OFF_BM  35389440                    // A bitmask 8192x1024B = 8388608

typedef __attribute__((ext_vector_type(8))) short  s16x8;
typedef __attribute__((ext_vector_type(4))) float  f32x4;

__device__ __forceinline__ unsigned short f2bf(float f) {
  unsigned int u = __float_as_uint(f);
  unsigned int r = (u + 0x7FFFu + ((u >> 16) & 1u)) >> 16;   // RNE
  return (unsigned short)r;
}

// ---------------- ka: pack A int32{0,1} -> 1 bit (pure streaming) ----------
// m13-shaped: dword-coalesced reads, no LDS/barriers, 32 waves/CU.
// Layout: bit l of ballot(word c) = A[row][seg*256 + c*64 + l]
//   -> byte b of row covers elements 8b..8b+7 in natural order.
__global__ __launch_bounds__(256) void ka_pack(const int* __restrict__ A,
                                               unsigned long long* __restrict__ BM) {
  int t = threadIdx.x;
  int l = t & 63, w = t >> 6;
  int row = blockIdx.x * 4 + w;
  const int* ap = A + (size_t)row * NN;
  unsigned long long* bp = BM + (size_t)row * (RBYTES / 8);
#pragma unroll 4
  for (int i = 0; i < 32; ++i) {
    int base = i * 256;
    int a0 = ap[base + l];
    int a1 = ap[base + 64 + l];
    int a2 = ap[base + 128 + l];
    int a3 = ap[base + 192 + l];
    unsigned long long w0 = __ballot(a0 > 0);
    unsigned long long w1 = __ballot(a1 > 0);
    unsigned long long w2 = __ballot(a2 > 0);
    unsigned long long w3 = __ballot(a3 > 0);
    if (l == 0) {
      bp[i * 4 + 0] = w0; bp[i * 4 + 1] = w1;
      bp[i * 4 + 2] = w2; bp[i * 4 + 3] = w3;
    }
  }
}

// ---------------- k1: h = X @ W (LDS-tiled fp32) -> fused e/HW write -------
__global__ __launch_bounds__(256) void k1_hw(const float* __restrict__ X,
                                             const float* __restrict__ W,
                                             const float* __restrict__ att,
                                             unsigned short* __restrict__ HW) {
  __shared__ float xs[16 * 516];
  __shared__ float ws[64 * 68];
  int t = threadIdx.x;
  int rb = blockIdx.x * 16;

  {
    const float4* src = (const float4*)(X + (size_t)rb * 512);
#pragma unroll
    for (int s = 0; s < 8; ++s) {
      int lid = s * 256 + t;
      int row = lid >> 7, kseg = lid & 127;
      *(float4*)&xs[row * 516 + kseg * 4] = src[row * 128 + kseg];
    }
  }

  int row = t >> 4, tx = t & 15;
  float4 acc = {0.f, 0.f, 0.f, 0.f};
  for (int kc = 0; kc < 8; ++kc) {
    __syncthreads();
#pragma unroll
    for (int s = 0; s < 4; ++s) {
      int lid = s * 256 + t;
      int k = lid >> 4, cs = lid & 15;
      *(float4*)&ws[k * 68 + cs * 4] =
          *(const float4*)(W + (size_t)(kc * 64 + k) * 64 + cs * 4);
    }
    __syncthreads();
#pragma unroll 16
    for (int k = 0; k < 64; ++k) {
      float x = xs[row * 516 + kc * 64 + k];
      float4 w4 = *(const float4*)&ws[k * 68 + tx * 4];
      acc.x += x * w4.x; acc.y += x * w4.y;
      acc.z += x * w4.z; acc.w += x * w4.w;
    }
  }

  float v = acc.x * att[64 + tx * 4]     + acc.y * att[64 + tx * 4 + 1] +
            acc.z * att[64 + tx * 4 + 2] + acc.w * att[64 + tx * 4 + 3];
#pragma unroll
  for (int m = 8; m > 0; m >>= 1) v += __shfl_xor(v, m, 64);
  float e = expf(v);                 // |r| <~ 21, no overflow

  int j = rb + row;
  unsigned short* hw = HW + j;
  float hv[4] = {acc.x, acc.y, acc.z, acc.w};
#pragma unroll
  for (int c = 0; c < 4; ++c)
    hw[(size_t)(tx * 4 + c) * NN] = f2bf(e * hv[c]);
  if (tx == 0) hw[(size_t)64 * NN] = f2bf(e);   // rows 65..79 never read
}

// ---------------- expand: 8 bits -> 8 bf16 {0,1} in A-frag order ----------
__device__ __forceinline__ s16x8 expand8(unsigned m) {
  union { unsigned u[4]; s16x8 v; } r;
#pragma unroll
  for (int j = 0; j < 4; ++j)
    r.u[j] = (((m >> (2 * j)) & 1u) | (((m >> (2 * j + 1)) & 1u) << 16)) * 0x3F80u;
  return r.v;
}

// ---------------- k3: bit-A (L1-resident) x LDS-resident swizzled B -------
// Block = (kc, mg): rows mg*128, K span [kc*512,+512). ONE barrier total.
// Per step: 4 ubyte loads (block bit-slice = 8KB, L1-hot) + in-register
// expand to A-frags + 20 MFMA. No A LDS tile, no per-step barriers.
__global__ __launch_bounds__(256, 2) void k3_gat(const unsigned char* __restrict__ BM,
                                                 const unsigned short* __restrict__ HW,
                                                 float* __restrict__ P) {
  __shared__ unsigned short bt[65 * 512];   // 66560 B, XOR-swizzled B

  int t = threadIdx.x;
  int kc = blockIdx.x & 15;                 // XCD-affine B slice
  int mg = blockIdx.x >> 4;                 // 0..63
  int lane = t & 63, w = t >> 6;
  int l15 = lane & 15, q = lane >> 4;
  int k0 = kc * CW;
  int rowM = mg * 128;

  // stage B swizzled: chunk ch of row goes to position ch ^ (row & 7)
#pragma unroll
  for (int rds = 0; rds < 16; ++rds) {
    int lid = rds * 256 + t;
    int row = lid >> 6, ch = lid & 63;
    uint4 v = *(const uint4*)(HW + (size_t)row * NN + k0 + ch * 8);
    *(uint4*)&bt[row * 512 + ((ch ^ (row & 7)) * 8)] = v;
  }
  if (t < 64) {                             // row 64 (e-row), unswizzled
    uint4 v = *(const uint4*)(HW + (size_t)64 * NN + k0 + t * 8);
    *(uint4*)&bt[64 * 512 + t * 8] = v;
  }
  __syncthreads();                          // the ONLY barrier

  // B ds_read byte-address bases (verified conflict-free in round 8)
  int swz = l15 & 7;
  int bb[4][2];
#pragma unroll
  for (int tt = 0; tt < 4; ++tt)
#pragma unroll
    for (int ks = 0; ks < 2; ++ks)
      bb[tt][ks] = ((tt * 16 + l15) * 512 + (((ks * 4 + q) ^ swz) * 8)) * 2;
  int eb0 = (64 * 512 + q * 8) * 2;
  int eb1 = (64 * 512 + (4 + q) * 8) * 2;

  // A-bit pointers: wave rows w*32 + mt*16 + l15; bytes kc*64 + s*8 + q (+4)
  const unsigned char* bmr[2];
#pragma unroll
  for (int mt = 0; mt < 2; ++mt)
    bmr[mt] = BM + (size_t)(rowM + w * 32 + mt * 16 + l15) * RBYTES + kc * 64 + q;

  f32x4 acc[2][5];
#pragma unroll
  for (int mt = 0; mt < 2; ++mt)
#pragma unroll
    for (int tt = 0; tt < 5; ++tt) acc[mt][tt] = 0.f;
  const s16x8 zero8 = {0, 0, 0, 0, 0, 0, 0, 0};

  unsigned c0[2], c1[2];
#pragma unroll
  for (int mt = 0; mt < 2; ++mt) { c0[mt] = bmr[mt][0]; c1[mt] = bmr[mt][4]; }

#pragma unroll
  for (int s = 0; s < 8; ++s) {
    unsigned n0[2], n1[2];
    if (s < 7) {
#pragma unroll
      for (int mt = 0; mt < 2; ++mt) {
        n0[mt] = bmr[mt][(s + 1) * 8];
        n1[mt] = bmr[mt][(s + 1) * 8 + 4];
      }
    }

    s16x8 af[2][2];
#pragma unroll
    for (int mt = 0; mt < 2; ++mt) {
      af[mt][0] = expand8(c0[mt]);
      af[mt][1] = expand8(c1[mt]);
    }

    int so = s * 128;                       // step byte offset within B row
#pragma unroll
    for (int ks = 0; ks < 2; ++ks) {
#pragma unroll
      for (int tt = 0; tt < 4; ++tt) {
        s16x8 b = *(const s16x8*)((char*)bt + bb[tt][ks] + so);
#pragma unroll
        for (int mt = 0; mt < 2; ++mt)
          acc[mt][tt] = __builtin_amdgcn_mfma_f32_16x16x32_bf16(af[mt][ks], b, acc[mt][tt], 0, 0, 0);
      }
      s16x8 b4 = *(const s16x8*)((char*)bt + (ks ? eb1 : eb0) + so);
      b4 = (l15 == 0) ? b4 : zero8;
#pragma unroll
      for (int mt = 0; mt < 2; ++mt)
        acc[mt][4] = __builtin_amdgcn_mfma_f32_16x16x32_bf16(af[mt][ks], b4, acc[mt][4], 0, 0, 0);
    }

#pragma unroll
    for (int mt = 0; mt < 2; ++mt) { c0[mt] = n0[mt]; c1[mt] = n1[mt]; }
  }

  // epilogue: C/D layout col=l15, row=q*4+rg
  float* Pp = P + (size_t)kc * NN * PSTR;
#pragma unroll
  for (int mt = 0; mt < 2; ++mt) {
    int rb = rowM + w * 32 + mt * 16 + q * 4;
#pragma unroll
    for (int tt = 0; tt < 4; ++tt)
#pragma unroll
      for (int rg = 0; rg < 4; ++rg)
        Pp[(size_t)(rb + rg) * PSTR + tt * 16 + l15] = acc[mt][tt][rg];
    if (l15 == 0)
#pragma unroll
      for (int rg = 0; rg < 4; ++rg)
        Pp[(size_t)(rb + rg) * PSTR + 64] = acc[mt][4][rg];
  }
}

// ---------------- k4: reduce 16 slabs + normalize + ELU ----------------
__global__ __launch_bounds__(256) void k4_fin(const float* __restrict__ P,
                                              float* __restrict__ out) {
  int g = blockIdx.x * 256 + threadIdx.x;          // 524288
  int i = g >> 6, c = g & 63;
  float num = 0.f, S = 0.f;
#pragma unroll
  for (int kc = 0; kc < KC; ++kc) {
    const float* p = P + (size_t)kc * NN * PSTR + (size_t)i * PSTR;
    num += p[c];
    S   += p[64];
  }
  float x = num / S;
  out[g] = x > 0.f ? x : expm1f(x);
}

extern "C" void kernel_launch(void* const* d_in, const int* in_sizes, int n_in,
                              void* d_out, int out_size, void* d_ws, size_t ws_size,
                              hipStream_t stream) {
  const float* X  = (const float*)d_in[0];   // 8192x512
  const int*   A  = (const int*)d_in[1];     // 8192x8192
  const float* W  = (const float*)d_in[2];   // 512x64
  const float* av = (const float*)d_in[3];   // 128x1
  float* out = (float*)d_out;

  char* ws = (char*)d_ws;
  unsigned short*     HW = (unsigned short*)(ws + OFF_HW);
  float*              P  = (float*)(ws + OFF_P);
  unsigned long long* BM = (unsigned long long*)(ws + OFF_BM);

  ka_pack<<<NN / 4, 256, 0, stream>>>(A, BM);
  k1_hw<<<NN / 16, 256, 0, stream>>>(X, W, av, HW);
  k3_gat<<<64 * KC, 256, 0, stream>>>((const unsigned char*)BM, HW, P);
  k4_fin<<<(size_t)NN * OF / 256, 256, 0, stream>>>(P, out);
}

// Round 10
// 411.233 us; speedup vs baseline: 1.0208x; 1.0208x over previous
//
#include <hip/hip_runtime.h>
#include <hip/hip_bf16.h>
#include <cstdint>

// ---------------- problem constants ----------------
#define NN      8192      // nodes
#define OF      64        // out features
#define KC      16        // K-chunks
#define CW      512       // K width per chunk (elements)
#define PSTR    65        // P slab row stride (floats): 64 cols + S
#define RBYTES  1024      // bitmask bytes per row (8192/8)

// ---------------- ws layout (bytes) ----------------
#define OFF_HW  0                           // HW 80x8192 u16       = 1310720
#define OFF_P   1310720                     // P16 16x8192x65 f32   = 34078720
#define OFF_BM  35389440                    // A bitmask 8192x1024B = 8388608

typedef __attribute__((ext_vector_type(8))) short  s16x8;
typedef __attribute__((ext_vector_type(4))) float  f32x4;

__device__ __forceinline__ unsigned short f2bf(float f) {
  unsigned int u = __float_as_uint(f);
  unsigned int r = (u + 0x7FFFu + ((u >> 16) & 1u)) >> 16;   // RNE
  return (unsigned short)r;
}

// ---------------- ka: pack A int32{0,1} -> 1 bit (true m13 shape) ----------
// Lane l packs elements [512i+8l, +8) -> byte (64i+l). No ballot, no LDS,
// no cross-lane; 16B/lane loads, 64B/wave coalesced byte stores, 32 waves/CU.
__global__ __launch_bounds__(256) void ka_pack(const int* __restrict__ A,
                                               unsigned char* __restrict__ BM) {
  int t = threadIdx.x;
  int l = t & 63, w = t >> 6;
  int row = blockIdx.x * 4 + w;
  const int* ap = A + (size_t)row * NN + l * 8;
  unsigned char* bp = BM + (size_t)row * RBYTES + l;
#pragma unroll 4
  for (int i = 0; i < 16; ++i) {
    int4 a = *(const int4*)(ap + i * 512);
    int4 b = *(const int4*)(ap + i * 512 + 4);
    unsigned by = (unsigned)(a.x | (a.y << 1) | (a.z << 2) | (a.w << 3) |
                             (b.x << 4) | (b.y << 5) | (b.z << 6) | (b.w << 7));
    bp[i * 64] = (unsigned char)by;
  }
}

// ---------------- k1: h = X @ W (LDS-tiled fp32) -> fused e/HW write -------
__global__ __launch_bounds__(256) void k1_hw(const float* __restrict__ X,
                                             const float* __restrict__ W,
                                             const float* __restrict__ att,
                                             unsigned short* __restrict__ HW) {
  __shared__ float xs[16 * 516];
  __shared__ float ws[64 * 68];
  int t = threadIdx.x;
  int rb = blockIdx.x * 16;

  {
    const float4* src = (const float4*)(X + (size_t)rb * 512);
#pragma unroll
    for (int s = 0; s < 8; ++s) {
      int lid = s * 256 + t;
      int row = lid >> 7, kseg = lid & 127;
      *(float4*)&xs[row * 516 + kseg * 4] = src[row * 128 + kseg];
    }
  }

  int row = t >> 4, tx = t & 15;
  float4 acc = {0.f, 0.f, 0.f, 0.f};
  for (int kc = 0; kc < 8; ++kc) {
    __syncthreads();
#pragma unroll
    for (int s = 0; s < 4; ++s) {
      int lid = s * 256 + t;
      int k = lid >> 4, cs = lid & 15;
      *(float4*)&ws[k * 68 + cs * 4] =
          *(const float4*)(W + (size_t)(kc * 64 + k) * 64 + cs * 4);
    }
    __syncthreads();
#pragma unroll 16
    for (int k = 0; k < 64; ++k) {
      float x = xs[row * 516 + kc * 64 + k];
      float4 w4 = *(const float4*)&ws[k * 68 + tx * 4];
      acc.x += x * w4.x; acc.y += x * w4.y;
      acc.z += x * w4.z; acc.w += x * w4.w;
    }
  }

  float v = acc.x * att[64 + tx * 4]     + acc.y * att[64 + tx * 4 + 1] +
            acc.z * att[64 + tx * 4 + 2] + acc.w * att[64 + tx * 4 + 3];
#pragma unroll
  for (int m = 8; m > 0; m >>= 1) v += __shfl_xor(v, m, 64);
  float e = expf(v);                 // |r| <~ 21, no overflow

  int j = rb + row;
  unsigned short* hw = HW + j;
  float hv[4] = {acc.x, acc.y, acc.z, acc.w};
#pragma unroll
  for (int c = 0; c < 4; ++c)
    hw[(size_t)(tx * 4 + c) * NN] = f2bf(e * hv[c]);
  if (tx == 0) hw[(size_t)64 * NN] = f2bf(e);   // rows 65..79 never read
}

// ---------------- expand: 8 bits -> 8 bf16 {0,1} in A-frag order ----------
__device__ __forceinline__ s16x8 expand8(unsigned m) {
  union { unsigned u[4]; s16x8 v; } r;
#pragma unroll
  for (int j = 0; j < 4; ++j)
    r.u[j] = (((m >> (2 * j)) & 1u) | (((m >> (2 * j + 1)) & 1u) << 16)) * 0x3F80u;
  return r.v;
}

__device__ __forceinline__ unsigned u4c(uint4 v, int c) {
  return c == 0 ? v.x : c == 1 ? v.y : c == 2 ? v.z : v.w;
}

// ---------------- k3: register-resident bit-A x LDS-resident swizzled B ---
// Each lane holds its whole A-bit slice (2 mt x 64B = 8 uint4) in VGPRs,
// loaded ONCE from L2 (~1MB hot/XCD). K-loop: LDS reads + expand + MFMA only
// -- zero global loads, zero barriers after the B-staging one.
__global__ __launch_bounds__(256, 2) void k3_gat(const unsigned char* __restrict__ BM,
                                                 const unsigned short* __restrict__ HW,
                                                 float* __restrict__ P) {
  __shared__ unsigned short bt[65 * 512];   // 66560 B, XOR-swizzled B

  int t = threadIdx.x;
  int kc = blockIdx.x & 15;                 // XCD-affine B slice
  int mg = blockIdx.x >> 4;                 // 0..63
  int lane = t & 63, w = t >> 6;
  int l15 = lane & 15, q = lane >> 4;
  int k0 = kc * CW;
  int rowM = mg * 128;

  // upfront A-bit load: lane's rows (mt=0,1), full 64B chunk each
  uint4 abits[2][4];
#pragma unroll
  for (int mt = 0; mt < 2; ++mt) {
    const uint4* p = (const uint4*)(BM +
        (size_t)(rowM + w * 32 + mt * 16 + l15) * RBYTES + kc * 64);
#pragma unroll
    for (int i = 0; i < 4; ++i) abits[mt][i] = p[i];
  }

  // stage B swizzled: chunk ch of row goes to position ch ^ (row & 7)
#pragma unroll
  for (int rds = 0; rds < 16; ++rds) {
    int lid = rds * 256 + t;
    int row = lid >> 6, ch = lid & 63;
    uint4 v = *(const uint4*)(HW + (size_t)row * NN + k0 + ch * 8);
    *(uint4*)&bt[row * 512 + ((ch ^ (row & 7)) * 8)] = v;
  }
  if (t < 64) {                             // row 64 (e-row), unswizzled
    uint4 v = *(const uint4*)(HW + (size_t)64 * NN + k0 + t * 8);
    *(uint4*)&bt[64 * 512 + t * 8] = v;
  }
  __syncthreads();                          // the ONLY barrier

  // B ds_read byte-address bases (round-8-verified conflict-free)
  int swz = l15 & 7;
  int bb[4][2];
#pragma unroll
  for (int tt = 0; tt < 4; ++tt)
#pragma unroll
    for (int ks = 0; ks < 2; ++ks)
      bb[tt][ks] = ((tt * 16 + l15) * 512 + (((ks * 4 + q) ^ swz) * 8)) * 2;
  int eb0 = (64 * 512 + q * 8) * 2;
  int eb1 = (64 * 512 + (4 + q) * 8) * 2;
  int qs = q * 8;

  f32x4 acc[2][5];
#pragma unroll
  for (int mt = 0; mt < 2; ++mt)
#pragma unroll
    for (int tt = 0; tt < 5; ++tt) acc[mt][tt] = 0.f;
  const s16x8 zero8 = {0, 0, 0, 0, 0, 0, 0, 0};

#pragma unroll
  for (int s = 0; s < 8; ++s) {
    // bytes {8s+q} (ks=0) and {8s+4+q} (ks=1) live in dwords 2s, 2s+1:
    // uint4 idx s>>1, components 2*(s&1) and 2*(s&1)+1 -- all static.
    s16x8 af[2][2];
#pragma unroll
    for (int mt = 0; mt < 2; ++mt) {
      unsigned d0 = u4c(abits[mt][s >> 1], 2 * (s & 1));
      unsigned d1 = u4c(abits[mt][s >> 1], 2 * (s & 1) + 1);
      af[mt][0] = expand8((d0 >> qs) & 0xFFu);
      af[mt][1] = expand8((d1 >> qs) & 0xFFu);
    }

    int so = s * 128;                       // step byte offset within B row
#pragma unroll
    for (int ks = 0; ks < 2; ++ks) {
#pragma unroll
      for (int tt = 0; tt < 4; ++tt) {
        s16x8 b = *(const s16x8*)((char*)bt + bb[tt][ks] + so);
#pragma unroll
        for (int mt = 0; mt < 2; ++mt)
          acc[mt][tt] = __builtin_amdgcn_mfma_f32_16x16x32_bf16(af[mt][ks], b, acc[mt][tt], 0, 0, 0);
      }
      s16x8 b4 = *(const s16x8*)((char*)bt + (ks ? eb1 : eb0) + so);
      b4 = (l15 == 0) ? b4 : zero8;
#pragma unroll
      for (int mt = 0; mt < 2; ++mt)
        acc[mt][4] = __builtin_amdgcn_mfma_f32_16x16x32_bf16(af[mt][ks], b4, acc[mt][4], 0, 0, 0);
    }
  }

  // epilogue: C/D layout col=l15, row=q*4+rg
  float* Pp = P + (size_t)kc * NN * PSTR;
#pragma unroll
  for (int mt = 0; mt < 2; ++mt) {
    int rb = rowM + w * 32 + mt * 16 + q * 4;
#pragma unroll
    for (int tt = 0; tt < 4; ++tt)
#pragma unroll
      for (int rg = 0; rg < 4; ++rg)
        Pp[(size_t)(rb + rg) * PSTR + tt * 16 + l15] = acc[mt][tt][rg];
    if (l15 == 0)
#pragma unroll
      for (int rg = 0; rg < 4; ++rg)
        Pp[(size_t)(rb + rg) * PSTR + 64] = acc[mt][4][rg];
  }
}

// ---------------- k4: reduce 16 slabs + normalize + ELU ----------------
__global__ __launch_bounds__(256) void k4_fin(const float* __restrict__ P,
                                              float* __restrict__ out) {
  int g = blockIdx.x * 256 + threadIdx.x;          // 524288
  int i = g >> 6, c = g & 63;
  float num = 0.f, S = 0.f;
#pragma unroll
  for (int kc = 0; kc < KC; ++kc) {
    const float* p = P + (size_t)kc * NN * PSTR + (size_t)i * PSTR;
    num += p[c];
    S   += p[64];
  }
  float x = num / S;
  out[g] = x > 0.f ? x : expm1f(x);
}

extern "C" void kernel_launch(void* const* d_in, const int* in_sizes, int n_in,
                              void* d_out, int out_size, void* d_ws, size_t ws_size,
                              hipStream_t stream) {
  const float* X  = (const float*)d_in[0];   // 8192x512
  const int*   A  = (const int*)d_in[1];     // 8192x8192
  const float* W  = (const float*)d_in[2];   // 512x64
  const float* av = (const float*)d_in[3];   // 128x1
  float* out = (float*)d_out;

  char* ws = (char*)d_ws;
  unsigned short* HW = (unsigned short*)(ws + OFF_HW);
  float*          P  = (float*)(ws + OFF_P);
  unsigned char*  BM = (unsigned char*)(ws + OFF_BM);

  ka_pack<<<NN / 4, 256, 0, stream>>>(A, BM);
  k1_hw<<<NN / 16, 256, 0, stream>>>(X, W, av, HW);
  k3_gat<<<64 * KC, 256, 0, stream>>>(BM, HW, P);
  k4_fin<<<(size_t)NN * OF / 256, 256, 0, stream>>>(P, out);
}